// Round 11
// baseline (235.610 us; speedup 1.0000x reference)
//
#include <hip/hip_runtime.h>
#include <hip/hip_bf16.h>
#include <hip/hip_fp16.h>
#include <stdint.h>

#define NF 64
#define NC 40
#define ZROW 64        // padded z row: 64 halves = 128 B = 2 full cache lines
#define ELLCAP 64      // neighbor slots per node (max deg ~38 for Poisson 12.5)

typedef _Float16 f16x8 __attribute__((ext_vector_type(8)));
typedef float f32x4 __attribute__((ext_vector_type(4)));

// ---------------------------------------------------------------------------
// Detect whether edge_index was uploaded as int32 or int64.
// ---------------------------------------------------------------------------
__global__ void detect_dtype_kernel(const unsigned int* __restrict__ p, int* __restrict__ flag,
                                    int n_check) {
    __shared__ int s_any;
    if (threadIdx.x == 0) s_any = 0;
    __syncthreads();
    int any = 0;
    for (int i = threadIdx.x; i < n_check; i += blockDim.x) {
        if (p[2 * i + 1] != 0u) any = 1;
    }
    if (any) atomicOr(&s_any, 1);
    __syncthreads();
    if (threadIdx.x == 0) *flag = s_any;
}

__device__ __forceinline__ long long load_idx(const void* p, long long i, int is32) {
    if (is32) return (long long)((const int*)p)[i];
    return ((const long long*)p)[i];
}

__global__ void zero_cnt_kernel(int* __restrict__ cnt, int N) {
    int i = blockIdx.x * blockDim.x + threadIdx.x;
    if (i < N) cnt[i] = 0;
}

// ---------------------------------------------------------------------------
// Fused kernel: blocks [0,gridZ) compute z_raw = x W^T via MFMA (16 nodes/wave,
// pad cols zeroed); blocks [gridZ, ...) count degrees + scatter neighbors into
// ELL (atomic return value = slot). The MFMA work hides under the atomic-bound
// count blocks. zgemm is dinv-independent (scaling deferred to finish_kernel).
// ---------------------------------------------------------------------------
__global__ void fused_count_zgemm_kernel(const float* __restrict__ x, const float* __restrict__ W,
                                         __half* __restrict__ z, const void* __restrict__ ei,
                                         int* __restrict__ cnt, int* __restrict__ ell,
                                         const int* __restrict__ flag, int N, long long E,
                                         int gridZ) {
    if ((int)blockIdx.x >= gridZ) {
        // ---- count + ELL scatter ----
        long long e = (long long)(blockIdx.x - gridZ) * blockDim.x + threadIdx.x;
        if (e >= E) return;
        int is32 = *flag;
        int r = (int)load_idx(ei, e, is32);
        int c = (int)load_idx(ei, E + e, is32);
        int pos = atomicAdd(&cnt[c], 1);
        if (pos < ELLCAP) ell[(size_t)c * ELLCAP + pos] = r;
        return;
    }

    // ---- zgemm: one wave = 16 nodes x 48 classes (3 MFMA class-tiles) ----
    int lane = threadIdx.x & 63;
    int wid = (blockIdx.x << 2) + ((threadIdx.x >> 6) & 3);
    int base = wid * 16;
    if (base >= N) return;

    int lrow = lane & 15;  // A row-in-tile / B class col / D class col
    int lk = lane >> 4;    // k-group (8 consecutive k each)

    f16x8 bfrag[3][2];
#pragma unroll
    for (int ct = 0; ct < 3; ++ct) {
        int wrow = ct * 16 + lrow;
        if (wrow > NC - 1) wrow = NC - 1;  // clamp pad classes (never stored)
        const float* wp = W + (size_t)wrow * NF;
#pragma unroll
        for (int kk = 0; kk < 2; ++kk) {
            float4 wa = *(const float4*)(wp + kk * 32 + lk * 8);
            float4 wb = *(const float4*)(wp + kk * 32 + lk * 8 + 4);
            f16x8 t;
            t[0] = (_Float16)wa.x; t[1] = (_Float16)wa.y;
            t[2] = (_Float16)wa.z; t[3] = (_Float16)wa.w;
            t[4] = (_Float16)wb.x; t[5] = (_Float16)wb.y;
            t[6] = (_Float16)wb.z; t[7] = (_Float16)wb.w;
            bfrag[ct][kk] = t;
        }
    }

    int arow = base + lrow;
    if (arow > N - 1) arow = N - 1;
    const float* xp = x + (size_t)arow * NF;
    f16x8 afrag[2];
#pragma unroll
    for (int kk = 0; kk < 2; ++kk) {
        float4 xa = *(const float4*)(xp + kk * 32 + lk * 8);
        float4 xb = *(const float4*)(xp + kk * 32 + lk * 8 + 4);
        f16x8 t;
        t[0] = (_Float16)xa.x; t[1] = (_Float16)xa.y;
        t[2] = (_Float16)xa.z; t[3] = (_Float16)xa.w;
        t[4] = (_Float16)xb.x; t[5] = (_Float16)xb.y;
        t[6] = (_Float16)xb.z; t[7] = (_Float16)xb.w;
        afrag[kk] = t;
    }

    f32x4 acc0 = {0.f, 0.f, 0.f, 0.f};
    f32x4 acc1 = {0.f, 0.f, 0.f, 0.f};
    f32x4 acc2 = {0.f, 0.f, 0.f, 0.f};
    acc0 = __builtin_amdgcn_mfma_f32_16x16x32_f16(afrag[0], bfrag[0][0], acc0, 0, 0, 0);
    acc0 = __builtin_amdgcn_mfma_f32_16x16x32_f16(afrag[1], bfrag[0][1], acc0, 0, 0, 0);
    acc1 = __builtin_amdgcn_mfma_f32_16x16x32_f16(afrag[0], bfrag[1][0], acc1, 0, 0, 0);
    acc1 = __builtin_amdgcn_mfma_f32_16x16x32_f16(afrag[1], bfrag[1][1], acc1, 0, 0, 0);
    acc2 = __builtin_amdgcn_mfma_f32_16x16x32_f16(afrag[0], bfrag[2][0], acc2, 0, 0, 0);
    acc2 = __builtin_amdgcn_mfma_f32_16x16x32_f16(afrag[1], bfrag[2][1], acc2, 0, 0, 0);

    // C/D mapping (m89-verified): col = lane&15, row = (lane>>4)*4 + reg.
#pragma unroll
    for (int r = 0; r < 4; ++r) {
        int row = base + lk * 4 + r;
        if (row >= N) break;
        __half* zr = z + (size_t)row * ZROW;
        zr[lrow] = __float2half(acc0[r]);                                  // 0..15
        zr[16 + lrow] = __float2half(acc1[r]);                             // 16..31
        zr[32 + lrow] = (lrow < 8) ? __float2half(acc2[r]) : __half(0.f);  // 32..47
        zr[48 + lrow] = __half(0.f);                                       // 48..63
    }
}

// dinv[i] = rsqrt(1+cnt[i]); z[i] *= dinv[i]  (32 lanes per node, coalesced)
__global__ void finish_kernel(const int* __restrict__ cnt, float* __restrict__ dinv,
                              __half* __restrict__ z, int N) {
    long long t = (long long)blockIdx.x * blockDim.x + threadIdx.x;
    int node = (int)(t >> 5);
    int p = (int)(t & 31);
    if (node >= N) return;
    float d = rsqrtf(1.0f + (float)cnt[node]);
    if (p == 0) dinv[node] = d;
    unsigned int* zp = (unsigned int*)z + (size_t)node * (ZROW / 2);
    unsigned int u = zp[p];
    float2 f = __half22float2(*reinterpret_cast<const __half2*>(&u));
    __half2 o = __float22half2_rn(make_float2(d * f.x, d * f.y));
    zp[p] = *reinterpret_cast<unsigned int*>(&o);
}

// Two nodes per wave; sub = lane&31 holds half2 (classes 2sub, 2sub+1).
// 4-deep load pipeline: 4 independent gathers in flight before first waitcnt.
__device__ __forceinline__ float2 hop_accum(const unsigned int* __restrict__ v32, int sub,
                                            int idx, const int* __restrict__ nl, int deg,
                                            int base, float2 acc) {
    int m = (deg < 32) ? deg : 32;
    int k = 0;
    for (; k + 4 <= m; k += 4) {
        int s0 = __shfl(idx, base + k + 0);
        int s1 = __shfl(idx, base + k + 1);
        int s2 = __shfl(idx, base + k + 2);
        int s3 = __shfl(idx, base + k + 3);
        unsigned int u0 = v32[(size_t)s0 * (ZROW / 2) + sub];
        unsigned int u1 = v32[(size_t)s1 * (ZROW / 2) + sub];
        unsigned int u2 = v32[(size_t)s2 * (ZROW / 2) + sub];
        unsigned int u3 = v32[(size_t)s3 * (ZROW / 2) + sub];
        float2 v0 = __half22float2(*reinterpret_cast<const __half2*>(&u0));
        float2 v1 = __half22float2(*reinterpret_cast<const __half2*>(&u1));
        float2 v2 = __half22float2(*reinterpret_cast<const __half2*>(&u2));
        float2 v3 = __half22float2(*reinterpret_cast<const __half2*>(&u3));
        acc.x += (v0.x + v1.x) + (v2.x + v3.x);
        acc.y += (v0.y + v1.y) + (v2.y + v3.y);
    }
    for (; k < m; ++k) {
        int s = __shfl(idx, base + k);
        unsigned int uu = v32[(size_t)s * (ZROW / 2) + sub];
        float2 v = __half22float2(*reinterpret_cast<const __half2*>(&uu));
        acc.x += v.x;
        acc.y += v.y;
    }
    for (k = 32; k < deg; ++k) {  // rare (max deg ~38)
        int s = nl[k];
        unsigned int uu = v32[(size_t)s * (ZROW / 2) + sub];
        float2 v = __half22float2(*reinterpret_cast<const __half2*>(&uu));
        acc.x += v.x;
        acc.y += v.y;
    }
    return acc;
}

__global__ void hop_kernel(const __half* __restrict__ vin, __half* __restrict__ vout,
                           const int* __restrict__ cnt, const int* __restrict__ ell,
                           const float* __restrict__ dinv, int N) {
    int t = blockIdx.x * blockDim.x + threadIdx.x;
    int lane = threadIdx.x & 63;
    int half = lane >> 5;
    int sub = lane & 31;
    int node = ((t >> 6) << 1) + half;
    if (node >= N) return;

    int deg = cnt[node];
    if (deg > ELLCAP) deg = ELLCAP;
    const int* nl = ell + (size_t)node * ELLCAP;

    const unsigned int* v32 = (const unsigned int*)vin;
    unsigned int u = v32[(size_t)node * (ZROW / 2) + sub];
    float2 acc = __half22float2(*reinterpret_cast<const __half2*>(&u));

    int idx = (sub < deg) ? nl[sub] : 0;
    acc = hop_accum(v32, sub, idx, nl, deg, half << 5, acc);

    float di = dinv[node];
    float d2 = di * di;
    __half2 o = __float22half2_rn(make_float2(d2 * acc.x, d2 * acc.y));
    ((unsigned int*)vout)[(size_t)node * (ZROW / 2) + sub] = *reinterpret_cast<unsigned int*>(&o);
}

// Final hop fused with bias + relu + log_softmax; reduction within each 32-lane
// half; direct contiguous float2 stores (160B per node).
__global__ void hop_final_kernel(const __half* __restrict__ vin, const float* __restrict__ b,
                                 float* __restrict__ out, const int* __restrict__ cnt,
                                 const int* __restrict__ ell, const float* __restrict__ dinv,
                                 int N) {
    int t = blockIdx.x * blockDim.x + threadIdx.x;
    int lane = threadIdx.x & 63;
    int half = lane >> 5;
    int sub = lane & 31;
    int node = ((t >> 6) << 1) + half;
    if (node >= N) return;

    int deg = cnt[node];
    if (deg > ELLCAP) deg = ELLCAP;
    const int* nl = ell + (size_t)node * ELLCAP;

    const unsigned int* v32 = (const unsigned int*)vin;
    unsigned int u = v32[(size_t)node * (ZROW / 2) + sub];
    float2 acc = __half22float2(*reinterpret_cast<const __half2*>(&u));

    int idx = (sub < deg) ? nl[sub] : 0;
    acc = hop_accum(v32, sub, idx, nl, deg, half << 5, acc);

    float di = dinv[node];
    float2 bv = (sub < NC / 2) ? ((const float2*)b)[sub] : make_float2(0.f, 0.f);
    float lx = fmaxf(di * acc.x + bv.x, 0.0f);  // pad lanes: acc=0,bv=0 -> 0
    float ly = fmaxf(di * acc.y + bv.y, 0.0f);

    float mx = fmaxf(lx, ly);
#pragma unroll
    for (int off = 16; off > 0; off >>= 1) mx = fmaxf(mx, __shfl_xor(mx, off));
    float e = (sub < NC / 2) ? (__expf(lx - mx) + __expf(ly - mx)) : 0.0f;
#pragma unroll
    for (int off = 16; off > 0; off >>= 1) e += __shfl_xor(e, off);
    float lse = mx + __logf(e);

    if (sub < NC / 2)
        ((float2*)out)[(size_t)node * (NC / 2) + sub] = make_float2(lx - lse, ly - lse);
}

extern "C" void kernel_launch(void* const* d_in, const int* in_sizes, int n_in,
                              void* d_out, int out_size, void* d_ws, size_t ws_size,
                              hipStream_t stream) {
    const float* x = (const float*)d_in[0];
    const void* ei = d_in[1];
    const float* W = (const float*)d_in[2];
    const float* b = (const float*)d_in[3];
    float* out = (float*)d_out;

    const int N = in_sizes[0] / NF;          // 100000
    const long long E = in_sizes[1] / 2;     // 1250000

    // workspace layout (256B aligned chunks)
    size_t off = 0;
    int* flag = (int*)((char*)d_ws + off);
    off += 256;
    int* cnt = (int*)((char*)d_ws + off);
    off += ((size_t)N * 4 + 255) & ~(size_t)255;
    float* dinv = (float*)((char*)d_ws + off);
    off += ((size_t)N * 4 + 255) & ~(size_t)255;
    int* ell = (int*)((char*)d_ws + off);
    off += ((size_t)N * ELLCAP * 4 + 255) & ~(size_t)255;   // 25.6 MB
    __half* z1 = (__half*)((char*)d_ws + off);
    size_t z_bytes = (size_t)N * ZROW * 2;
    off += (z_bytes + 255) & ~(size_t)255;
    __half* z2 = (__half*)((char*)d_ws + off);
    off += (z_bytes + 255) & ~(size_t)255;
    if (off > ws_size) return;

    const int B = 256;
    int gridN = (N + B - 1) / B;
    long long hopThreads = ((long long)(N + 1) / 2) * 64;  // 2 nodes per wave
    int gridH = (int)((hopThreads + B - 1) / B);

    // 0. dtype detection
    int n_check = (int)((E < 4096) ? E : 4096);
    detect_dtype_kernel<<<1, 256, 0, stream>>>((const unsigned int*)ei, flag, n_check);

    // 1. zero degree counters
    zero_cnt_kernel<<<gridN, B, 0, stream>>>(cnt, N);

    // 2. fused: z_raw = x W^T (MFMA) || degree count + ELL scatter
    int gridZ = (((N + 15) / 16) + 3) / 4;        // 4 waves/block
    int gridC = (int)((E + B - 1) / B);
    fused_count_zgemm_kernel<<<gridZ + gridC, B, 0, stream>>>(x, W, z1, ei, cnt, ell, flag, N, E,
                                                              gridZ);

    // 3. dinv = rsqrt(1+deg); z1 *= dinv (row-wise)
    finish_kernel<<<(int)(((long long)N * 32 + B - 1) / B), B, 0, stream>>>(cnt, dinv, z1, N);

    // 4. hops 1,2 in class space (fp16); hop 3 fused with bias+relu+log_softmax
    hop_kernel<<<gridH, B, 0, stream>>>(z1, z2, cnt, ell, dinv, N);
    hop_kernel<<<gridH, B, 0, stream>>>(z2, z1, cnt, ell, dinv, N);
    hop_final_kernel<<<gridH, B, 0, stream>>>(z1, b, out, cnt, ell, dinv, N);
}

// Round 12
// 181.089 us; speedup vs baseline: 1.3011x; 1.3011x over previous
//
#include <hip/hip_runtime.h>
#include <hip/hip_bf16.h>
#include <hip/hip_fp16.h>
#include <stdint.h>

#define NF 64
#define NC 40
#define ZROW 64        // padded z row: 64 halves = 128 B
#define ELLCAP 64      // neighbor slots per node (max deg ~38 for Poisson 12.5)

typedef _Float16 f16x8 __attribute__((ext_vector_type(8)));
typedef float f32x4 __attribute__((ext_vector_type(4)));

// ---------------------------------------------------------------------------
// Detect whether edge_index was uploaded as int32 or int64.
// ---------------------------------------------------------------------------
__global__ void detect_dtype_kernel(const unsigned int* __restrict__ p, int* __restrict__ flag,
                                    int n_check) {
    __shared__ int s_any;
    if (threadIdx.x == 0) s_any = 0;
    __syncthreads();
    int any = 0;
    for (int i = threadIdx.x; i < n_check; i += blockDim.x) {
        if (p[2 * i + 1] != 0u) any = 1;
    }
    if (any) atomicOr(&s_any, 1);
    __syncthreads();
    if (threadIdx.x == 0) *flag = s_any;
}

__device__ __forceinline__ long long load_idx(const void* p, long long i, int is32) {
    if (is32) return (long long)((const int*)p)[i];
    return ((const long long*)p)[i];
}

__global__ void zero_cnt_kernel(int* __restrict__ cnt, int N) {
    int i = blockIdx.x * blockDim.x + threadIdx.x;
    if (i < N) cnt[i] = 0;
}

// cnt[col[e]] += 1; epos[e] = slot (atomic return value). No scans needed.
__global__ void count_kernel(const void* __restrict__ ei, int* __restrict__ cnt,
                             int* __restrict__ epos, const int* __restrict__ flag, long long E) {
    long long e = (long long)blockIdx.x * blockDim.x + threadIdx.x;
    if (e >= E) return;
    int is32 = *flag;
    int c = (int)load_idx(ei, E + e, is32);
    epos[e] = atomicAdd(&cnt[c], 1);
}

// dinv[i] = rsqrt(1 + deg)
__global__ void dinv_kernel(const int* __restrict__ cnt, float* __restrict__ dinv, int N) {
    int i = blockIdx.x * blockDim.x + threadIdx.x;
    if (i < N) dinv[i] = rsqrtf(1.0f + (float)cnt[i]);
}

// ell[c*ELLCAP + epos[e]] = r   (pure scatter, no atomics)
__global__ void ell_fill_kernel(const void* __restrict__ ei, const int* __restrict__ epos,
                                int* __restrict__ ell, const int* __restrict__ flag, long long E) {
    long long e = (long long)blockIdx.x * blockDim.x + threadIdx.x;
    if (e >= E) return;
    int is32 = *flag;
    int r = (int)load_idx(ei, e, is32);
    int c = (int)load_idx(ei, E + e, is32);
    int pos = epos[e];
    if (pos < ELLCAP) ell[(size_t)c * ELLCAP + pos] = r;
}

// z[i][c] = half( dinv[i] * sum_f x[i][f] * W[c][f] ) via MFMA, 16 nodes/wave.
// Pad columns (40..63) are never written: they never influence real outputs.
__global__ void zgemm_mfma_kernel(const float* __restrict__ x, const float* __restrict__ W,
                                  const float* __restrict__ dinv, __half* __restrict__ z,
                                  int N) {
    int lane = threadIdx.x & 63;
    int wid = (blockIdx.x * blockDim.x + threadIdx.x) >> 6;
    int base = wid * 16;
    if (base >= N) return;

    int lrow = lane & 15;  // A row-in-tile / B class col / D class col
    int lk = lane >> 4;    // k-group (8 consecutive k each)

    f16x8 bfrag[3][2];
#pragma unroll
    for (int ct = 0; ct < 3; ++ct) {
        int wrow = ct * 16 + lrow;
        if (wrow > NC - 1) wrow = NC - 1;  // clamp pad classes (never stored)
        const float* wp = W + (size_t)wrow * NF;
#pragma unroll
        for (int kk = 0; kk < 2; ++kk) {
            float4 wa = *(const float4*)(wp + kk * 32 + lk * 8);
            float4 wb = *(const float4*)(wp + kk * 32 + lk * 8 + 4);
            f16x8 t;
            t[0] = (_Float16)wa.x; t[1] = (_Float16)wa.y;
            t[2] = (_Float16)wa.z; t[3] = (_Float16)wa.w;
            t[4] = (_Float16)wb.x; t[5] = (_Float16)wb.y;
            t[6] = (_Float16)wb.z; t[7] = (_Float16)wb.w;
            bfrag[ct][kk] = t;
        }
    }

    int arow = base + lrow;
    if (arow > N - 1) arow = N - 1;
    const float* xp = x + (size_t)arow * NF;
    f16x8 afrag[2];
#pragma unroll
    for (int kk = 0; kk < 2; ++kk) {
        float4 xa = *(const float4*)(xp + kk * 32 + lk * 8);
        float4 xb = *(const float4*)(xp + kk * 32 + lk * 8 + 4);
        f16x8 t;
        t[0] = (_Float16)xa.x; t[1] = (_Float16)xa.y;
        t[2] = (_Float16)xa.z; t[3] = (_Float16)xa.w;
        t[4] = (_Float16)xb.x; t[5] = (_Float16)xb.y;
        t[6] = (_Float16)xb.z; t[7] = (_Float16)xb.w;
        afrag[kk] = t;
    }

    f32x4 acc0 = {0.f, 0.f, 0.f, 0.f};
    f32x4 acc1 = {0.f, 0.f, 0.f, 0.f};
    f32x4 acc2 = {0.f, 0.f, 0.f, 0.f};
    acc0 = __builtin_amdgcn_mfma_f32_16x16x32_f16(afrag[0], bfrag[0][0], acc0, 0, 0, 0);
    acc0 = __builtin_amdgcn_mfma_f32_16x16x32_f16(afrag[1], bfrag[0][1], acc0, 0, 0, 0);
    acc1 = __builtin_amdgcn_mfma_f32_16x16x32_f16(afrag[0], bfrag[1][0], acc1, 0, 0, 0);
    acc1 = __builtin_amdgcn_mfma_f32_16x16x32_f16(afrag[1], bfrag[1][1], acc1, 0, 0, 0);
    acc2 = __builtin_amdgcn_mfma_f32_16x16x32_f16(afrag[0], bfrag[2][0], acc2, 0, 0, 0);
    acc2 = __builtin_amdgcn_mfma_f32_16x16x32_f16(afrag[1], bfrag[2][1], acc2, 0, 0, 0);

    float4 dv = *(const float4*)(dinv + base + lk * 4);

    // C/D mapping (m89-verified): col = lane&15, row = (lane>>4)*4 + reg.
#pragma unroll
    for (int r = 0; r < 4; ++r) {
        int row = base + lk * 4 + r;
        if (row >= N) break;
        float d = (r == 0) ? dv.x : (r == 1) ? dv.y : (r == 2) ? dv.z : dv.w;
        __half* zr = z + (size_t)row * ZROW;
        zr[lrow] = __float2half(d * acc0[r]);                     // classes 0..15
        zr[16 + lrow] = __float2half(d * acc1[r]);                // classes 16..31
        if (lrow < 8) zr[32 + lrow] = __float2half(d * acc2[r]);  // classes 32..39
    }
}

// ---------------------------------------------------------------------------
// Hop kernels: 8 nodes per wave (8 groups x 8 lanes). Lane jg of group g holds
// classes [8jg..8jg+7] of node (wave*8+g). One gather instruction = 8 full
// 128B rows. ELL slots preloaded as int4; intra-group shfl broadcast (branch
// cond is group-uniform -> shfl sources always active). fp32 accumulate.
// ---------------------------------------------------------------------------
__device__ __forceinline__ void add_row(float2 (&acc)[4], float4 raw) {
    union { float4 f; __half2 h[4]; } u;
    u.f = raw;
#pragma unroll
    for (int q = 0; q < 4; ++q) {
        float2 t = __half22float2(u.h[q]);
        acc[q].x += t.x;
        acc[q].y += t.y;
    }
}

__device__ __forceinline__ void gather_rows(float2 (&acc)[4], const float4* __restrict__ vp,
                                            const int* __restrict__ ell_row, int deg, int wmax,
                                            int base, int jg) {
    const int4* ep = (const int4*)ell_row;
    int4 ia = ep[jg];  // slots 4jg..4jg+3
#pragma unroll
    for (int r = 0; r < 4; ++r) {
        int ir = (r == 0) ? ia.x : (r == 1) ? ia.y : (r == 2) ? ia.z : ia.w;
#pragma unroll
        for (int j = 0; j < 8; ++j) {
            if (4 * j + r < deg) {  // group-uniform
                int s = __shfl(ir, base + j);
                add_row(acc, vp[(size_t)s * 8 + jg]);
            }
        }
    }
    if (wmax > 32) {  // wave-uniform; essentially never taken (max deg ~38 < 32? guard anyway)
        int4 ib = ep[8 + jg];  // slots 32+4jg..
#pragma unroll
        for (int r = 0; r < 4; ++r) {
            int ir = (r == 0) ? ib.x : (r == 1) ? ib.y : (r == 2) ? ib.z : ib.w;
#pragma unroll
            for (int j = 0; j < 8; ++j) {
                if (32 + 4 * j + r < deg) {
                    int s = __shfl(ir, base + j);
                    add_row(acc, vp[(size_t)s * 8 + jg]);
                }
            }
        }
    }
}

__global__ void hop_kernel(const __half* __restrict__ vin, __half* __restrict__ vout,
                           const int* __restrict__ cnt, const int* __restrict__ ell,
                           const float* __restrict__ dinv, int N) {
    int lane = threadIdx.x & 63;
    int g = lane >> 3, jg = lane & 7;
    int wave = (int)(((long long)blockIdx.x * blockDim.x + threadIdx.x) >> 6);
    int node = wave * 8 + g;
    bool valid = node < N;
    int nc = valid ? node : N - 1;

    int deg = cnt[nc];
    if (deg > ELLCAP) deg = ELLCAP;
    int wmax = deg;
    wmax = max(wmax, __shfl_xor(wmax, 8));
    wmax = max(wmax, __shfl_xor(wmax, 16));
    wmax = max(wmax, __shfl_xor(wmax, 32));

    const float4* vp = (const float4*)vin;
    float2 acc[4];
    add_row(*(float2(*)[4]) & acc, make_float4(0, 0, 0, 0));  // no-op keep type happy
#pragma unroll
    for (int q = 0; q < 4; ++q) acc[q] = make_float2(0.f, 0.f);
    add_row(acc, vp[(size_t)nc * 8 + jg]);  // self term

    gather_rows(acc, vp, ell + (size_t)nc * ELLCAP, deg, wmax, lane & 56, jg);

    if (valid) {
        float d = dinv[node];
        float d2 = d * d;
        union { float4 f; __half2 h[4]; } o;
#pragma unroll
        for (int q = 0; q < 4; ++q)
            o.h[q] = __float22half2_rn(make_float2(d2 * acc[q].x, d2 * acc[q].y));
        ((float4*)vout)[(size_t)node * 8 + jg] = o.f;
    }
}

__global__ void hop_final_kernel(const __half* __restrict__ vin, const float* __restrict__ b,
                                 float* __restrict__ out, const int* __restrict__ cnt,
                                 const int* __restrict__ ell, const float* __restrict__ dinv,
                                 int N) {
    int lane = threadIdx.x & 63;
    int g = lane >> 3, jg = lane & 7;
    int wave = (int)(((long long)blockIdx.x * blockDim.x + threadIdx.x) >> 6);
    int node = wave * 8 + g;
    bool valid = node < N;
    int nc = valid ? node : N - 1;

    int deg = cnt[nc];
    if (deg > ELLCAP) deg = ELLCAP;
    int wmax = deg;
    wmax = max(wmax, __shfl_xor(wmax, 8));
    wmax = max(wmax, __shfl_xor(wmax, 16));
    wmax = max(wmax, __shfl_xor(wmax, 32));

    const float4* vp = (const float4*)vin;
    float2 acc[4];
#pragma unroll
    for (int q = 0; q < 4; ++q) acc[q] = make_float2(0.f, 0.f);
    add_row(acc, vp[(size_t)nc * 8 + jg]);  // self term

    gather_rows(acc, vp, ell + (size_t)nc * ELLCAP, deg, wmax, lane & 56, jg);

    float d = dinv[nc];
    float2 bv[4];
#pragma unroll
    for (int q = 0; q < 4; ++q) bv[q] = make_float2(0.f, 0.f);
    if (jg < 5) {
        float4 b0 = ((const float4*)b)[2 * jg];
        float4 b1 = ((const float4*)b)[2 * jg + 1];
        bv[0] = make_float2(b0.x, b0.y);
        bv[1] = make_float2(b0.z, b0.w);
        bv[2] = make_float2(b1.x, b1.y);
        bv[3] = make_float2(b1.z, b1.w);
    }

    float2 l[4];
#pragma unroll
    for (int q = 0; q < 4; ++q) {
        l[q].x = fmaxf(d * acc[q].x + bv[q].x, 0.0f);
        l[q].y = fmaxf(d * acc[q].y + bv[q].y, 0.0f);
        if (jg >= 5) l[q] = make_float2(0.f, 0.f);  // mask pad classes
    }

    // group-local max (real logits >= 0, pads hold 0 -> harmless)
    float mx = 0.0f;
#pragma unroll
    for (int q = 0; q < 4; ++q) mx = fmaxf(mx, fmaxf(l[q].x, l[q].y));
    mx = fmaxf(mx, __shfl_xor(mx, 1));
    mx = fmaxf(mx, __shfl_xor(mx, 2));
    mx = fmaxf(mx, __shfl_xor(mx, 4));

    float e = 0.0f;
    if (jg < 5) {
#pragma unroll
        for (int q = 0; q < 4; ++q) e += __expf(l[q].x - mx) + __expf(l[q].y - mx);
    }
    e += __shfl_xor(e, 1);
    e += __shfl_xor(e, 2);
    e += __shfl_xor(e, 4);
    float lse = mx + __logf(e);

    if (valid && jg < 5) {
        float4 o0 = make_float4(l[0].x - lse, l[0].y - lse, l[1].x - lse, l[1].y - lse);
        float4 o1 = make_float4(l[2].x - lse, l[2].y - lse, l[3].x - lse, l[3].y - lse);
        float4* op = (float4*)out + (size_t)node * 10 + 2 * jg;
        op[0] = o0;
        op[1] = o1;
    }
}

extern "C" void kernel_launch(void* const* d_in, const int* in_sizes, int n_in,
                              void* d_out, int out_size, void* d_ws, size_t ws_size,
                              hipStream_t stream) {
    const float* x = (const float*)d_in[0];
    const void* ei = d_in[1];
    const float* W = (const float*)d_in[2];
    const float* b = (const float*)d_in[3];
    float* out = (float*)d_out;

    const int N = in_sizes[0] / NF;          // 100000
    const long long E = in_sizes[1] / 2;     // 1250000

    // workspace layout (256B aligned chunks)
    size_t off = 0;
    int* flag = (int*)((char*)d_ws + off);
    off += 256;
    int* cnt = (int*)((char*)d_ws + off);
    off += ((size_t)N * 4 + 255) & ~(size_t)255;
    float* dinv = (float*)((char*)d_ws + off);
    off += ((size_t)N * 4 + 255) & ~(size_t)255;
    int* epos = (int*)((char*)d_ws + off);
    off += ((size_t)E * 4 + 255) & ~(size_t)255;
    int* ell = (int*)((char*)d_ws + off);
    off += ((size_t)N * ELLCAP * 4 + 255) & ~(size_t)255;   // 25.6 MB
    __half* z1 = (__half*)((char*)d_ws + off);
    size_t z_bytes = (size_t)N * ZROW * 2;
    off += (z_bytes + 255) & ~(size_t)255;
    __half* z2 = (__half*)((char*)d_ws + off);
    off += (z_bytes + 255) & ~(size_t)255;
    if (off > ws_size) return;

    const int B = 256;
    int gridN = (N + B - 1) / B;
    int gridE = (int)((E + B - 1) / B);
    long long hopThreads = (((long long)N + 7) / 8) * 64;  // 8 nodes per wave
    int gridH = (int)((hopThreads + B - 1) / B);

    // 0. dtype detection
    int n_check = (int)((E < 4096) ? E : 4096);
    detect_dtype_kernel<<<1, 256, 0, stream>>>((const unsigned int*)ei, flag, n_check);

    // 1. graph build: zero -> count(+slots) -> dinv -> ELL scatter (no scans)
    zero_cnt_kernel<<<gridN, B, 0, stream>>>(cnt, N);
    count_kernel<<<gridE, B, 0, stream>>>(ei, cnt, epos, flag, E);
    dinv_kernel<<<gridN, B, 0, stream>>>(cnt, dinv, N);
    ell_fill_kernel<<<gridE, B, 0, stream>>>(ei, epos, ell, flag, E);

    // 2. v0 = D^{-1/2} (x W^T) [N,64-padded] fp16 via MFMA (16 nodes/wave)
    int gridZ = (((N + 15) / 16) + 3) / 4;
    zgemm_mfma_kernel<<<gridZ, 256, 0, stream>>>(x, W, dinv, z1, N);

    // 3. hops 1,2 (fp16, 8 nodes/wave); hop 3 fused with bias+relu+log_softmax
    hop_kernel<<<gridH, B, 0, stream>>>(z1, z2, cnt, ell, dinv, N);
    hop_kernel<<<gridH, B, 0, stream>>>(z2, z1, cnt, ell, dinv, N);
    hop_final_kernel<<<gridH, B, 0, stream>>>(z1, b, out, cnt, ell, dinv, N);
}